// Round 9
// baseline (284.601 us; speedup 1.0000x reference)
//
#include <hip/hip_runtime.h>

#define D_MODEL 1024
#define D_STATE 16
#define D_INNER 2048
#define DT_RANK 64
#define NBATCH 2
#define SEQ_L 1024
#define M_ROWS (NBATCH * SEQ_L)   // 2048
#define CHUNK 64
#define NCHUNK (SEQ_L / CHUNK)    // 16

typedef __bf16 bf16x8 __attribute__((ext_vector_type(8)));
typedef float f32x4 __attribute__((ext_vector_type(4)));
typedef unsigned short u16;
typedef unsigned int u32;

__device__ __forceinline__ float bf2f(u16 h) {
    return __uint_as_float(((unsigned)h) << 16);
}
__device__ __forceinline__ u16 f2bf(float f) {
    unsigned u = __float_as_uint(f);
    u += 0x7fff + ((u >> 16) & 1);   // round-to-nearest-even
    return (u16)(u >> 16);
}

// ---------------- prep: weight casts (blocks 0..25855) + LayerNorm (rest) ----------------
__global__ __launch_bounds__(256) void prep(
    const float* __restrict__ s0, const float* __restrict__ s1,
    const float* __restrict__ s2, const float* __restrict__ s3,
    u16* __restrict__ d0, u16* __restrict__ d1,
    u16* __restrict__ d2, u16* __restrict__ d3,
    const float* __restrict__ x, const float* __restrict__ g,
    const float* __restrict__ b, u16* __restrict__ xn) {
    int blk = blockIdx.x;
    if (blk < 25856) {
        int idx = blk * 256 + threadIdx.x;
        if (idx < 4194304) {
            d0[idx] = f2bf(s0[idx]);
        } else if (idx < 6291456) {
            int i = idx - 4194304; d1[i] = f2bf(s1[i]);
        } else if (idx < 6488064) {
            int i = idx - 6291456; d2[i] = f2bf(s2[i]);
        } else {
            int i = idx - 6488064; d3[i] = f2bf(s3[i]);
        }
        return;
    }
    int row = blk - 25856;
    const float4* xr = (const float4*)(x + (size_t)row * D_MODEL);
    float4 v = xr[threadIdx.x];
    float s  = v.x + v.y + v.z + v.w;
    float ss = v.x * v.x + v.y * v.y + v.z * v.z + v.w * v.w;
#pragma unroll
    for (int off = 32; off > 0; off >>= 1) {
        s  += __shfl_down(s,  off, 64);
        ss += __shfl_down(ss, off, 64);
    }
    __shared__ float sh_s[4], sh_ss[4];
    int wid = threadIdx.x >> 6;
    if ((threadIdx.x & 63) == 0) { sh_s[wid] = s; sh_ss[wid] = ss; }
    __syncthreads();
    float mu  = (sh_s[0] + sh_s[1] + sh_s[2] + sh_s[3]) * (1.0f / D_MODEL);
    float var = (sh_ss[0] + sh_ss[1] + sh_ss[2] + sh_ss[3]) * (1.0f / D_MODEL) - mu * mu;
    float rs = rsqrtf(var + 1e-5f);
    int c0 = threadIdx.x * 4;
    float vv[4] = {v.x, v.y, v.z, v.w};
#pragma unroll
    for (int j = 0; j < 4; j++) {
        int c = c0 + j;
        float o = (vv[j] - mu) * rs * g[c] + b[c];
        xn[(size_t)row * D_MODEL + c] = f2bf(o);
    }
}

// ============ LDS-staged B^T GEMM (m97 structure) ============
// K-split over blockIdx.z (Ksteps iters from z*Ksteps*32).
// MODE 0: bf16 store. MODE 4: f32 partial store to outF + z*M_ROWS*ldC.
template <int BM, int BN, int WM, int WN, int MODE>
__global__ __launch_bounds__(256) void gemm_lds(
    const __bf16* __restrict__ A, const __bf16* __restrict__ W,
    int K, int Ksteps, int ldC,
    float* __restrict__ outF, u16* __restrict__ outB) {
    constexpr int WCOLS = BN / (WN * 16);
    __shared__ __bf16 As[BM * 32];
    __shared__ __bf16 Bs[BN * 32];
    int tid  = threadIdx.x;
    int lane = tid & 63;
    int wid  = tid >> 6;
    int l16  = lane & 15;
    int quad = lane >> 4;
    int wr = wid / WCOLS;
    int wc = wid % WCOLS;
    int m0 = blockIdx.y * BM;
    int n0 = blockIdx.x * BN;
    int kbase = blockIdx.z * Ksteps * 32;

    f32x4 acc[WM][WN];
#pragma unroll
    for (int mi = 0; mi < WM; mi++)
#pragma unroll
        for (int nj = 0; nj < WN; nj++)
            acc[mi][nj] = (f32x4){0.f, 0.f, 0.f, 0.f};

    for (int ki = 0; ki < Ksteps; ki++) {
        int k0 = kbase + ki * 32;
        __syncthreads();
#pragma unroll
        for (int i = 0; i < BM / 64; i++) {
            int t   = i * 256 + tid;
            int row = t >> 2;
            int cg  = (t & 3) ^ ((row >> 1) & 3);
            __builtin_amdgcn_global_load_lds(
                (const __attribute__((address_space(1))) u32*)(A + (size_t)(m0 + row) * K + k0 + cg * 8),
                (__attribute__((address_space(3))) u32*)(As + (i * 256 + wid * 64) * 8),
                16, 0, 0);
        }
#pragma unroll
        for (int i = 0; i < BN / 64; i++) {
            int t   = i * 256 + tid;
            int row = t >> 2;
            int cg  = (t & 3) ^ ((row >> 1) & 3);
            __builtin_amdgcn_global_load_lds(
                (const __attribute__((address_space(1))) u32*)(W + (size_t)(n0 + row) * K + k0 + cg * 8),
                (__attribute__((address_space(3))) u32*)(Bs + (i * 256 + wid * 64) * 8),
                16, 0, 0);
        }
        __syncthreads();

        bf16x8 af[WM], bfr[WN];
#pragma unroll
        for (int mi = 0; mi < WM; mi++) {
            int r  = wr * WM * 16 + mi * 16 + l16;
            int cg = quad ^ ((r >> 1) & 3);
            af[mi] = *(const bf16x8*)(As + r * 32 + cg * 8);
        }
#pragma unroll
        for (int nj = 0; nj < WN; nj++) {
            int r  = wc * WN * 16 + nj * 16 + l16;
            int cg = quad ^ ((r >> 1) & 3);
            bfr[nj] = *(const bf16x8*)(Bs + r * 32 + cg * 8);
        }
#pragma unroll
        for (int mi = 0; mi < WM; mi++)
#pragma unroll
            for (int nj = 0; nj < WN; nj++)
                acc[mi][nj] = __builtin_amdgcn_mfma_f32_16x16x32_bf16(
                    af[mi], bfr[nj], acc[mi][nj], 0, 0, 0);
    }

    float* outP = (MODE == 4) ? outF + (size_t)blockIdx.z * M_ROWS * ldC : outF;
#pragma unroll
    for (int mi = 0; mi < WM; mi++) {
#pragma unroll
        for (int nj = 0; nj < WN; nj++) {
            int col = n0 + wc * WN * 16 + nj * 16 + l16;
#pragma unroll
            for (int r = 0; r < 4; r++) {
                int row = m0 + wr * WM * 16 + mi * 16 + quad * 4 + r;
                float v = acc[mi][nj][r];
                if (MODE == 0) {
                    outB[(size_t)row * ldC + col] = f2bf(v);
                } else {
                    outP[(size_t)row * ldC + col] = v;
                }
            }
        }
    }
}

// ---------------- out_proj partial reduce + residual ----------------
__global__ __launch_bounds__(256) void out_reduce(
    const float* __restrict__ p, const float* __restrict__ x,
    float* __restrict__ out) {
    int idx = blockIdx.x * 256 + threadIdx.x;   // float4 index
    const int N = M_ROWS * D_MODEL;
    float4 a = ((const float4*)p)[idx];
    float4 b = ((const float4*)(p + N))[idx];
    float4 c = ((const float4*)(p + 2 * N))[idx];
    float4 d = ((const float4*)(p + 3 * N))[idx];
    float4 r = ((const float4*)x)[idx];
    float4 o;
    o.x = a.x + b.x + c.x + d.x + r.x;
    o.y = a.y + b.y + c.y + d.y + r.y;
    o.z = a.z + b.z + c.z + d.z + r.z;
    o.w = a.w + b.w + c.w + d.w + r.w;
    ((float4*)out)[idx] = o;
}

// ---------------- x_proj direct GEMM, K-split partials ----------------
__global__ __launch_bounds__(256) void gemm_xproj(
    const __bf16* __restrict__ A, const __bf16* __restrict__ W,
    int K, int Ksplit, int Nw, int ldC, float* __restrict__ outF) {
    int lane = threadIdx.x & 63;
    int wid  = threadIdx.x >> 6;
    int m0 = blockIdx.y * 64;
    int n0 = blockIdx.x * 64;
    int kc = blockIdx.z;
    int l16  = lane & 15;
    int quad = lane >> 4;
    int mrow = m0 + wid * 16 + l16;

    const __bf16* ap = A + (size_t)mrow * K + kc * Ksplit + quad * 8;
    const __bf16* wp[4];
#pragma unroll
    for (int j = 0; j < 4; j++) {
        int nc = n0 + j * 16 + l16;
        if (nc > Nw - 1) nc = Nw - 1;
        wp[j] = W + (size_t)nc * K + kc * Ksplit + quad * 8;
    }
    f32x4 acc[4];
#pragma unroll
    for (int j = 0; j < 4; j++) acc[j] = (f32x4){0.f, 0.f, 0.f, 0.f};

    for (int k = 0; k < Ksplit; k += 32) {
        bf16x8 a = *(const bf16x8*)ap;
        ap += 32;
#pragma unroll
        for (int j = 0; j < 4; j++) {
            bf16x8 bfr = *(const bf16x8*)wp[j];
            wp[j] += 32;
            acc[j] = __builtin_amdgcn_mfma_f32_16x16x32_bf16(a, bfr, acc[j], 0, 0, 0);
        }
    }
    float* out = outF + (size_t)kc * (M_ROWS * 96);
#pragma unroll
    for (int j = 0; j < 4; j++) {
        int col = n0 + j * 16 + l16;
#pragma unroll
        for (int r = 0; r < 4; r++) {
            int row = m0 + wid * 16 + quad * 4 + r;
            if (col < Nw) out[(size_t)row * ldC + col] = acc[j][r];
        }
    }
}

// ---------------- reduce 8 K-split partials -> xd, fused dt bf16 cast ----------------
__global__ __launch_bounds__(256) void xdbl_reduce(
    const float* __restrict__ xdp, float* __restrict__ xd,
    u16* __restrict__ dtb) {
    int idx = blockIdx.x * 256 + threadIdx.x;   // < M_ROWS*96
    const int N = M_ROWS * 96;
    float v = 0.f;
#pragma unroll
    for (int i = 0; i < 8; i++) v += xdp[idx + i * N];
    xd[idx] = v;
    int mrow = idx / 96;
    int r = idx - mrow * 96;
    if (r < DT_RANK) dtb[mrow * DT_RANK + r] = f2bf(v);
}

// ---------------- causal depthwise conv (width 4) + bias + SiLU ----------------
__global__ __launch_bounds__(256) void conv_silu(
    const u16* __restrict__ xz, const float* __restrict__ cw,
    const float* __restrict__ cb, u16* __restrict__ uc) {
    int idx = blockIdx.x * 256 + threadIdx.x;
    int d = idx & (D_INNER - 1);
    int m = idx >> 11;
    int t = m & (SEQ_L - 1);
    float s = cb[d];
#pragma unroll
    for (int j = 0; j < 4; j++) {
        int tt = t - 3 + j;
        if (tt >= 0) {
            s += cw[d * 4 + j] *
                 bf2f(xz[(size_t)(m - 3 + j) * (2 * D_INNER) + d]);
        }
    }
    float sig = 1.f / (1.f + __expf(-s));
    uc[idx] = f2bf(s * sig);
}

// ================= chunked selective scan, fused dt_proj+softplus =================
// Block = (chunk c, 64-d group, batch b). Prologue: delta tile [64 t][64 d] =
// softplus(dtb[64x64] @ w_dt^T[64x64] + bias) via 8 MFMA/wave -> LDS dlS.
// Thread layout: dsub = lane&15, g = lane>>4 (4 states each), dloc = w*16+dsub.
// In-loop dl reads are 16-address LDS broadcasts (conflict-free).

__device__ __forceinline__ void delta_tile(
    const __bf16* __restrict__ dtb, const __bf16* __restrict__ wdt,
    const float* __restrict__ dtbias, int mbase, int d0,
    int w, int l16, int quad, float (*dlS)[64]) {
    f32x4 acc[4];
#pragma unroll
    for (int j = 0; j < 4; j++) acc[j] = (f32x4){0.f, 0.f, 0.f, 0.f};
    const __bf16* ap = dtb + (size_t)(mbase + w * 16 + l16) * DT_RANK + quad * 8;
#pragma unroll
    for (int kk = 0; kk < 2; kk++) {
        bf16x8 av = *(const bf16x8*)(ap + kk * 32);
#pragma unroll
        for (int j = 0; j < 4; j++) {
            bf16x8 bv = *(const bf16x8*)(wdt +
                (size_t)(d0 + j * 16 + l16) * DT_RANK + kk * 32 + quad * 8);
            acc[j] = __builtin_amdgcn_mfma_f32_16x16x32_bf16(av, bv, acc[j], 0, 0, 0);
        }
    }
#pragma unroll
    for (int j = 0; j < 4; j++) {
        int dcol = j * 16 + l16;
        float bias = dtbias[d0 + dcol];
#pragma unroll
        for (int r = 0; r < 4; r++) {
            float tv = acc[j][r] + bias;
            dlS[w * 16 + quad * 4 + r][dcol] = (tv > 20.f) ? tv : log1pf(__expf(tv));
        }
    }
}

__global__ __launch_bounds__(256) void scan_chunk(
    const __bf16* __restrict__ dtb, const __bf16* __restrict__ wdt,
    const float* __restrict__ dtbias,
    const u16* __restrict__ uc, const float* __restrict__ xd,
    const float* __restrict__ A_log,
    float* __restrict__ Pst, float* __restrict__ Sst) {
    __shared__ float dlS[CHUNK][64];
    __shared__ float Bsh[CHUNK][16];
    int tid  = threadIdx.x;
    int lane = tid & 63;
    int w    = tid >> 6;
    int dsub = lane & 15;
    int g    = lane >> 4;
    int n0   = g * 4;
    int c = blockIdx.x, b = blockIdx.z;
    int d0 = blockIdx.y * 64;
    int dloc = w * 16 + dsub;
    int d = d0 + dloc;
    int mbase = b * SEQ_L + c * CHUNK;

    delta_tile(dtb, wdt, dtbias, mbase, d0, w, dsub, g, dlS);
    {
        int row = tid >> 2, q = tid & 3;
        *(float4*)&Bsh[row][q * 4] =
            *(const float4*)(xd + (size_t)(mbase + row) * 96 + DT_RANK + q * 4);
    }
    __syncthreads();

    float a[4];
    {
        float4 a0 = *(const float4*)(A_log + d * D_STATE + n0);
        a[0] = -__expf(a0.x); a[1] = -__expf(a0.y);
        a[2] = -__expf(a0.z); a[3] = -__expf(a0.w);
    }
    float P[4] = {1.f, 1.f, 1.f, 1.f}, S[4] = {0.f, 0.f, 0.f, 0.f};

    for (int t0 = 0; t0 < CHUNK; t0 += 4) {
        float dlv[4], uv[4];
#pragma unroll
        for (int i = 0; i < 4; i++) {
            int m = mbase + t0 + i;
            uv[i]  = bf2f(uc[(size_t)m * D_INNER + d]);
            dlv[i] = dlS[t0 + i][dloc];
        }
#pragma unroll
        for (int i = 0; i < 4; i++) {
            float c1 = dlv[i] * uv[i];
#pragma unroll
            for (int j = 0; j < 4; j++) {
                float dA = __expf(dlv[i] * a[j]);
                P[j] *= dA;
                S[j] = dA * S[j] + c1 * Bsh[t0 + i][n0 + j];
            }
        }
    }
    size_t s = ((size_t)(b * D_INNER + d) * NCHUNK + c) * D_STATE + n0;
    *(float4*)(Pst + s) = (float4){P[0], P[1], P[2], P[3]};
    *(float4*)(Sst + s) = (float4){S[0], S[1], S[2], S[3]};
}

__global__ __launch_bounds__(256) void scan_combine(
    const float* __restrict__ Pst, const float* __restrict__ Sst,
    float* __restrict__ Hin) {
    int idx = blockIdx.x * 256 + threadIdx.x;
    int bd = idx >> 4;
    int n  = idx & 15;
    float h = 0.f;
#pragma unroll
    for (int c = 0; c < NCHUNK; ++c) {
        size_t s = ((size_t)bd * NCHUNK + c) * D_STATE + n;
        Hin[s] = h;
        h = Pst[s] * h + Sst[s];
    }
}

__global__ __launch_bounds__(256) void scan_apply(
    const __bf16* __restrict__ dtb, const __bf16* __restrict__ wdt,
    const float* __restrict__ dtbias,
    const u16* __restrict__ uc, const float* __restrict__ xd,
    const u16* __restrict__ xz, const float* __restrict__ A_log,
    const float* __restrict__ Dsk, const float* __restrict__ Hin,
    u16* __restrict__ yg) {
    __shared__ float dlS[CHUNK][64];
    __shared__ float BCs[CHUNK][32];
    int tid  = threadIdx.x;
    int lane = tid & 63;
    int w    = tid >> 6;
    int dsub = lane & 15;
    int g    = lane >> 4;
    int n0   = g * 4;
    int c = blockIdx.x, b = blockIdx.z;
    int d0 = blockIdx.y * 64;
    int dloc = w * 16 + dsub;
    int d = d0 + dloc;
    int mbase = b * SEQ_L + c * CHUNK;

    delta_tile(dtb, wdt, dtbias, mbase, d0, w, dsub, g, dlS);
    {
#pragma unroll
        for (int i = 0; i < 2; i++) {
            int idx = i * 256 + tid;
            int row = idx >> 3, q = idx & 7;
            *(float4*)&BCs[row][q * 4] =
                *(const float4*)(xd + (size_t)(mbase + row) * 96 + DT_RANK + q * 4);
        }
    }
    __syncthreads();

    float a[4];
    {
        float4 a0 = *(const float4*)(A_log + d * D_STATE + n0);
        a[0] = -__expf(a0.x); a[1] = -__expf(a0.y);
        a[2] = -__expf(a0.z); a[3] = -__expf(a0.w);
    }
    float h[4];
    {
        float4 h0 = *(const float4*)(Hin +
            (((size_t)(b * D_INNER + d) * NCHUNK + c) * D_STATE + n0));
        h[0] = h0.x; h[1] = h0.y; h[2] = h0.z; h[3] = h0.w;
    }
    float dsk = Dsk[d];

    for (int t0 = 0; t0 < CHUNK; t0 += 4) {
        float dlv[4], uv[4], zv[4];
#pragma unroll
        for (int i = 0; i < 4; i++) {
            int m = mbase + t0 + i;
            uv[i]  = bf2f(uc[(size_t)m * D_INNER + d]);
            zv[i]  = bf2f(xz[(size_t)m * (2 * D_INNER) + D_INNER + d]);
            dlv[i] = dlS[t0 + i][dloc];
        }
#pragma unroll
        for (int i = 0; i < 4; i++) {
            int t = t0 + i;
            float c1 = dlv[i] * uv[i];
            float y = 0.f;
#pragma unroll
            for (int j = 0; j < 4; j++) {
                float dA = __expf(dlv[i] * a[j]);
                h[j] = dA * h[j] + c1 * BCs[t][n0 + j];
                y += h[j] * BCs[t][16 + n0 + j];
            }
            y += __shfl_xor(y, 16);
            y += __shfl_xor(y, 32);
            if (g == 0) {
                float z = zv[i];
                float yv = y + uv[i] * dsk;
                float gt = z / (1.f + __expf(-z));
                yg[(size_t)(mbase + t) * D_INNER + d] = f2bf(yv * gt);
            }
        }
    }
}

extern "C" void kernel_launch(void* const* d_in, const int* in_sizes, int n_in,
                              void* d_out, int out_size, void* d_ws, size_t ws_size,
                              hipStream_t stream) {
    const float* x         = (const float*)d_in[0];
    const float* ln_g      = (const float*)d_in[1];
    const float* ln_b      = (const float*)d_in[2];
    const float* in_proj_w = (const float*)d_in[3];
    const float* conv_w    = (const float*)d_in[4];
    const float* conv_b    = (const float*)d_in[5];
    const float* x_proj_w  = (const float*)d_in[6];
    const float* dt_proj_w = (const float*)d_in[7];
    const float* dt_proj_b = (const float*)d_in[8];
    const float* A_log     = (const float*)d_in[9];
    const float* Dsk       = (const float*)d_in[10];
    const float* out_proj_w= (const float*)d_in[11];

    char* ws = (char*)d_ws;
    u16* xn   = (u16*)ws;    ws += (size_t)M_ROWS * D_MODEL * 2;        // 4 MB
    u16* xz   = (u16*)ws;    ws += (size_t)M_ROWS * 2 * D_INNER * 2;    // 16 MB
    u16* ucv  = (u16*)ws;    ws += (size_t)M_ROWS * D_INNER * 2;        // 8 MB
    float* xd = (float*)ws;  ws += (size_t)M_ROWS * 96 * 4;             // 0.75 MB
    u16* dtb  = (u16*)ws;    ws += (size_t)M_ROWS * DT_RANK * 2;        // 0.25 MB
    /* dead 16 MB slot (was dl) — kept so the opart overlay below has room */
    ws += (size_t)M_ROWS * D_INNER * 4;
    u16* yg   = (u16*)ws;    ws += (size_t)M_ROWS * D_INNER * 2;        // 8 MB
    u16* w_in = (u16*)ws;    ws += (size_t)4194304 * 2;                 // 8 MB
    u16* w_out= (u16*)ws;    ws += (size_t)2097152 * 2;                 // 4 MB
    u16* w_xp = (u16*)ws;    ws += (size_t)196608 * 2;                  // 0.375 MB
    u16* w_dt = (u16*)ws;                                               // 0.25 MB

    // Overlays (stream-ordered safe):
    //   Pst -> w_in[0,4MB), Sst -> w_in[4MB,8MB)  (w_in dead after in_proj GEMM)
    //   Hin -> xn (dead after in_proj GEMM)
    //   xdp (x_proj K-split partials, 8 x 0.79MB) -> yg (dead until scan_apply)
    //   opart (out_proj partials, 32MB) -> xz..dead-slot (all dead after scan_apply)
    float* Pst = (float*)w_in;
    float* Sst = (float*)w_in + 1048576;
    float* Hin = (float*)xn;
    float* xdp = (float*)yg;
    float* opart = (float*)xz;

    // 0. weight casts + LayerNorm (one dispatch)
    prep<<<25856 + M_ROWS, 256, 0, stream>>>(
        in_proj_w, out_proj_w, x_proj_w, dt_proj_w, w_in, w_out, w_xp, w_dt,
        x, ln_g, ln_b, xn);
    // 1. xz = xn @ in_proj_w^T  (M=2048, N=4096, K=1024) — 64x128 tile, 1024 blocks
    gemm_lds<64, 128, 4, 2, 0><<<dim3(4096 / 128, M_ROWS / 64, 1), 256, 0, stream>>>(
        (const __bf16*)xn, (const __bf16*)w_in, D_MODEL, D_MODEL / 32, 2 * D_INNER,
        nullptr, xz);
    // 2. causal depthwise conv + SiLU on u half
    conv_silu<<<(M_ROWS * D_INNER) / 256, 256, 0, stream>>>(xz, conv_w, conv_b, ucv);
    // 3. x_dbl partials = u @ x_proj_w^T  (N=96, K-split by 8) + fused reduce/cast
    gemm_xproj<<<dim3(2, 32, 8), 256, 0, stream>>>(
        (const __bf16*)ucv, (const __bf16*)w_xp, D_INNER, D_INNER / 8, 96, 96, xdp);
    xdbl_reduce<<<(M_ROWS * 96) / 256, 256, 0, stream>>>(xdp, xd, dtb);
    // 4. chunked selective scan with fused dt_proj+softplus (1024 blocks each)
    dim3 sgrid(NCHUNK, D_INNER / 64, NBATCH);
    scan_chunk<<<sgrid, 256, 0, stream>>>(
        (const __bf16*)dtb, (const __bf16*)w_dt, dt_proj_b, ucv, xd, A_log, Pst, Sst);
    scan_combine<<<(NBATCH * D_INNER * D_STATE) / 256, 256, 0, stream>>>(Pst, Sst, Hin);
    scan_apply<<<sgrid, 256, 0, stream>>>(
        (const __bf16*)dtb, (const __bf16*)w_dt, dt_proj_b, ucv, xd, xz,
        A_log, Dsk, Hin, yg);
    // 5. out_proj partials (K=2048 split x4) + reduce w/ residual
    gemm_lds<64, 128, 4, 2, 4><<<dim3(1024 / 128, M_ROWS / 64, 4), 256, 0, stream>>>(
        (const __bf16*)yg, (const __bf16*)w_out, D_INNER, D_INNER / 4 / 32, D_MODEL,
        opart, nullptr);
    out_reduce<<<(M_ROWS * D_MODEL / 4) / 256, 256, 0, stream>>>(
        opart, x, (float*)d_out);
}

// Round 10
// 272.495 us; speedup vs baseline: 1.0444x; 1.0444x over previous
//
#include <hip/hip_runtime.h>

#define D_MODEL 1024
#define D_STATE 16
#define D_INNER 2048
#define DT_RANK 64
#define NBATCH 2
#define SEQ_L 1024
#define M_ROWS (NBATCH * SEQ_L)   // 2048
#define CHUNK 64
#define NCHUNK (SEQ_L / CHUNK)    // 16

typedef __bf16 bf16x8 __attribute__((ext_vector_type(8)));
typedef float f32x4 __attribute__((ext_vector_type(4)));
typedef unsigned short u16;
typedef unsigned int u32;

__device__ __forceinline__ float bf2f(u16 h) {
    return __uint_as_float(((unsigned)h) << 16);
}
__device__ __forceinline__ u16 f2bf(float f) {
    unsigned u = __float_as_uint(f);
    u += 0x7fff + ((u >> 16) & 1);   // round-to-nearest-even
    return (u16)(u >> 16);
}

// ---------------- prep: weight casts (blocks 0..25855) + LayerNorm (rest) ----------------
__global__ __launch_bounds__(256) void prep(
    const float* __restrict__ s0, const float* __restrict__ s1,
    const float* __restrict__ s2, const float* __restrict__ s3,
    u16* __restrict__ d0, u16* __restrict__ d1,
    u16* __restrict__ d2, u16* __restrict__ d3,
    const float* __restrict__ x, const float* __restrict__ g,
    const float* __restrict__ b, u16* __restrict__ xn) {
    int blk = blockIdx.x;
    if (blk < 25856) {
        int idx = blk * 256 + threadIdx.x;
        if (idx < 4194304) {
            d0[idx] = f2bf(s0[idx]);
        } else if (idx < 6291456) {
            int i = idx - 4194304; d1[i] = f2bf(s1[i]);
        } else if (idx < 6488064) {
            int i = idx - 6291456; d2[i] = f2bf(s2[i]);
        } else {
            int i = idx - 6488064; d3[i] = f2bf(s3[i]);
        }
        return;
    }
    int row = blk - 25856;
    const float4* xr = (const float4*)(x + (size_t)row * D_MODEL);
    float4 v = xr[threadIdx.x];
    float s  = v.x + v.y + v.z + v.w;
    float ss = v.x * v.x + v.y * v.y + v.z * v.z + v.w * v.w;
#pragma unroll
    for (int off = 32; off > 0; off >>= 1) {
        s  += __shfl_down(s,  off, 64);
        ss += __shfl_down(ss, off, 64);
    }
    __shared__ float sh_s[4], sh_ss[4];
    int wid = threadIdx.x >> 6;
    if ((threadIdx.x & 63) == 0) { sh_s[wid] = s; sh_ss[wid] = ss; }
    __syncthreads();
    float mu  = (sh_s[0] + sh_s[1] + sh_s[2] + sh_s[3]) * (1.0f / D_MODEL);
    float var = (sh_ss[0] + sh_ss[1] + sh_ss[2] + sh_ss[3]) * (1.0f / D_MODEL) - mu * mu;
    float rs = rsqrtf(var + 1e-5f);
    int c0 = threadIdx.x * 4;
    float vv[4] = {v.x, v.y, v.z, v.w};
#pragma unroll
    for (int j = 0; j < 4; j++) {
        int c = c0 + j;
        float o = (vv[j] - mu) * rs * g[c] + b[c];
        xn[(size_t)row * D_MODEL + c] = f2bf(o);
    }
}

// ============ LDS-staged B^T GEMM (m97 structure) ============
// K-split over blockIdx.z (Ksteps iters from z*Ksteps*32).
// MODE 0: bf16 store. MODE 4: f32 partial store to outF + z*M_ROWS*ldC.
template <int BM, int BN, int WM, int WN, int MODE>
__global__ __launch_bounds__(256) void gemm_lds(
    const __bf16* __restrict__ A, const __bf16* __restrict__ W,
    int K, int Ksteps, int ldC,
    float* __restrict__ outF, u16* __restrict__ outB) {
    constexpr int WCOLS = BN / (WN * 16);
    __shared__ __bf16 As[BM * 32];
    __shared__ __bf16 Bs[BN * 32];
    int tid  = threadIdx.x;
    int lane = tid & 63;
    int wid  = tid >> 6;
    int l16  = lane & 15;
    int quad = lane >> 4;
    int wr = wid / WCOLS;
    int wc = wid % WCOLS;
    int m0 = blockIdx.y * BM;
    int n0 = blockIdx.x * BN;
    int kbase = blockIdx.z * Ksteps * 32;

    f32x4 acc[WM][WN];
#pragma unroll
    for (int mi = 0; mi < WM; mi++)
#pragma unroll
        for (int nj = 0; nj < WN; nj++)
            acc[mi][nj] = (f32x4){0.f, 0.f, 0.f, 0.f};

    for (int ki = 0; ki < Ksteps; ki++) {
        int k0 = kbase + ki * 32;
        __syncthreads();
#pragma unroll
        for (int i = 0; i < BM / 64; i++) {
            int t   = i * 256 + tid;
            int row = t >> 2;
            int cg  = (t & 3) ^ ((row >> 1) & 3);
            __builtin_amdgcn_global_load_lds(
                (const __attribute__((address_space(1))) u32*)(A + (size_t)(m0 + row) * K + k0 + cg * 8),
                (__attribute__((address_space(3))) u32*)(As + (i * 256 + wid * 64) * 8),
                16, 0, 0);
        }
#pragma unroll
        for (int i = 0; i < BN / 64; i++) {
            int t   = i * 256 + tid;
            int row = t >> 2;
            int cg  = (t & 3) ^ ((row >> 1) & 3);
            __builtin_amdgcn_global_load_lds(
                (const __attribute__((address_space(1))) u32*)(W + (size_t)(n0 + row) * K + k0 + cg * 8),
                (__attribute__((address_space(3))) u32*)(Bs + (i * 256 + wid * 64) * 8),
                16, 0, 0);
        }
        __syncthreads();

        bf16x8 af[WM], bfr[WN];
#pragma unroll
        for (int mi = 0; mi < WM; mi++) {
            int r  = wr * WM * 16 + mi * 16 + l16;
            int cg = quad ^ ((r >> 1) & 3);
            af[mi] = *(const bf16x8*)(As + r * 32 + cg * 8);
        }
#pragma unroll
        for (int nj = 0; nj < WN; nj++) {
            int r  = wc * WN * 16 + nj * 16 + l16;
            int cg = quad ^ ((r >> 1) & 3);
            bfr[nj] = *(const bf16x8*)(Bs + r * 32 + cg * 8);
        }
#pragma unroll
        for (int mi = 0; mi < WM; mi++)
#pragma unroll
            for (int nj = 0; nj < WN; nj++)
                acc[mi][nj] = __builtin_amdgcn_mfma_f32_16x16x32_bf16(
                    af[mi], bfr[nj], acc[mi][nj], 0, 0, 0);
    }

    float* outP = (MODE == 4) ? outF + (size_t)blockIdx.z * M_ROWS * ldC : outF;
#pragma unroll
    for (int mi = 0; mi < WM; mi++) {
#pragma unroll
        for (int nj = 0; nj < WN; nj++) {
            int col = n0 + wc * WN * 16 + nj * 16 + l16;
#pragma unroll
            for (int r = 0; r < 4; r++) {
                int row = m0 + wr * WM * 16 + mi * 16 + quad * 4 + r;
                float v = acc[mi][nj][r];
                if (MODE == 0) {
                    outB[(size_t)row * ldC + col] = f2bf(v);
                } else {
                    outP[(size_t)row * ldC + col] = v;
                }
            }
        }
    }
}

// ---------------- out_proj partial reduce + residual ----------------
__global__ __launch_bounds__(256) void out_reduce(
    const float* __restrict__ p, const float* __restrict__ x,
    float* __restrict__ out) {
    int idx = blockIdx.x * 256 + threadIdx.x;   // float4 index
    const int N = M_ROWS * D_MODEL;
    float4 a = ((const float4*)p)[idx];
    float4 b = ((const float4*)(p + N))[idx];
    float4 c = ((const float4*)(p + 2 * N))[idx];
    float4 d = ((const float4*)(p + 3 * N))[idx];
    float4 r = ((const float4*)x)[idx];
    float4 o;
    o.x = a.x + b.x + c.x + d.x + r.x;
    o.y = a.y + b.y + c.y + d.y + r.y;
    o.z = a.z + b.z + c.z + d.z + r.z;
    o.w = a.w + b.w + c.w + d.w + r.w;
    ((float4*)out)[idx] = o;
}

// ---------------- small direct GEMM (x_proj K-split / dt_proj) ----------------
// MODE 1: partial f32 to outF + z*M_ROWS*96, col<Nw.  MODE 2: softplus(acc+auxF[n]).
template <int MODE>
__global__ __launch_bounds__(256) void gemm_bt(
    const __bf16* __restrict__ A, const __bf16* __restrict__ W,
    int K, int Ksplit, int Nw, int ldC,
    float* __restrict__ outF, const float* __restrict__ auxF) {
    int lane = threadIdx.x & 63;
    int wid  = threadIdx.x >> 6;
    int m0 = blockIdx.y * 64;
    int n0 = blockIdx.x * 64;
    int kc = blockIdx.z;
    int l16  = lane & 15;
    int quad = lane >> 4;
    int mrow = m0 + wid * 16 + l16;

    const __bf16* ap = A + (size_t)mrow * K + kc * Ksplit + quad * 8;
    const __bf16* wp[4];
#pragma unroll
    for (int j = 0; j < 4; j++) {
        int nc = n0 + j * 16 + l16;
        if (nc > Nw - 1) nc = Nw - 1;
        wp[j] = W + (size_t)nc * K + kc * Ksplit + quad * 8;
    }
    f32x4 acc[4];
#pragma unroll
    for (int j = 0; j < 4; j++) acc[j] = (f32x4){0.f, 0.f, 0.f, 0.f};

    for (int k = 0; k < Ksplit; k += 32) {
        bf16x8 a = *(const bf16x8*)ap;
        ap += 32;
#pragma unroll
        for (int j = 0; j < 4; j++) {
            bf16x8 bfr = *(const bf16x8*)wp[j];
            wp[j] += 32;
            acc[j] = __builtin_amdgcn_mfma_f32_16x16x32_bf16(a, bfr, acc[j], 0, 0, 0);
        }
    }
    float* out = (MODE == 1) ? outF + (size_t)kc * (M_ROWS * 96) : outF;
#pragma unroll
    for (int j = 0; j < 4; j++) {
        int col = n0 + j * 16 + l16;
#pragma unroll
        for (int r = 0; r < 4; r++) {
            int row = m0 + wid * 16 + quad * 4 + r;
            float v = acc[j][r];
            if (MODE == 1) {
                if (col < Nw) out[(size_t)row * ldC + col] = v;
            } else {
                float t = v + auxF[col];
                float sp = (t > 20.f) ? t : log1pf(__expf(t));
                out[(size_t)row * ldC + col] = sp;
            }
        }
    }
}

// ---------------- reduce 8 K-split partials -> xd, fused dt bf16 cast ----------------
__global__ __launch_bounds__(256) void xdbl_reduce(
    const float* __restrict__ xdp, float* __restrict__ xd,
    u16* __restrict__ dtb) {
    int idx = blockIdx.x * 256 + threadIdx.x;   // < M_ROWS*96
    const int N = M_ROWS * 96;
    float v = 0.f;
#pragma unroll
    for (int i = 0; i < 8; i++) v += xdp[idx + i * N];
    xd[idx] = v;
    int mrow = idx / 96;
    int r = idx - mrow * 96;
    if (r < DT_RANK) dtb[mrow * DT_RANK + r] = f2bf(v);
}

// ---------------- causal depthwise conv (width 4) + bias + SiLU ----------------
__global__ __launch_bounds__(256) void conv_silu(
    const u16* __restrict__ xz, const float* __restrict__ cw,
    const float* __restrict__ cb, u16* __restrict__ uc) {
    int idx = blockIdx.x * 256 + threadIdx.x;
    int d = idx & (D_INNER - 1);
    int m = idx >> 11;
    int t = m & (SEQ_L - 1);
    float s = cb[d];
#pragma unroll
    for (int j = 0; j < 4; j++) {
        int tt = t - 3 + j;
        if (tt >= 0) {
            s += cw[d * 4 + j] *
                 bf2f(xz[(size_t)(m - 3 + j) * (2 * D_INNER) + d]);
        }
    }
    float sig = 1.f / (1.f + __expf(-s));
    uc[idx] = f2bf(s * sig);
}

// ================= chunked selective scan — 4 states/thread, unroll-4 =================
// (r8-verified version: dl read from global; no in-kernel dt_proj recompute —
//  r9's fused delta_tile regressed scan_apply 30→56 µs via duplicated softplus
//  + LDS write conflicts. Do not re-fuse.)
__global__ __launch_bounds__(256) void scan_chunk(
    const float* __restrict__ delta, const u16* __restrict__ uc,
    const float* __restrict__ xd, const float* __restrict__ A_log,
    float* __restrict__ Pst, float* __restrict__ Sst) {
    __shared__ float Bsh[CHUNK][16];
    int tid  = threadIdx.x;
    int lane = tid & 63;
    int w    = tid >> 6;
    int dsub = lane & 15;
    int g    = lane >> 4;
    int n0   = g * 4;
    int c = blockIdx.x, b = blockIdx.z;
    int d = blockIdx.y * 64 + w * 16 + dsub;
    int mbase = b * SEQ_L + c * CHUNK;

    {
        int row = tid >> 2, q = tid & 3;
        *(float4*)&Bsh[row][q * 4] =
            *(const float4*)(xd + (size_t)(mbase + row) * 96 + DT_RANK + q * 4);
    }
    __syncthreads();

    float a[4];
    {
        float4 a0 = *(const float4*)(A_log + d * D_STATE + n0);
        a[0] = -__expf(a0.x); a[1] = -__expf(a0.y);
        a[2] = -__expf(a0.z); a[3] = -__expf(a0.w);
    }
    float P[4] = {1.f, 1.f, 1.f, 1.f}, S[4] = {0.f, 0.f, 0.f, 0.f};

    for (int t0 = 0; t0 < CHUNK; t0 += 4) {
        float dlv[4], uv[4];
#pragma unroll
        for (int i = 0; i < 4; i++) {
            int m = mbase + t0 + i;
            dlv[i] = delta[(size_t)m * D_INNER + d];
            uv[i]  = bf2f(uc[(size_t)m * D_INNER + d]);
        }
#pragma unroll
        for (int i = 0; i < 4; i++) {
            float c1 = dlv[i] * uv[i];
#pragma unroll
            for (int j = 0; j < 4; j++) {
                float dA = __expf(dlv[i] * a[j]);
                P[j] *= dA;
                S[j] = dA * S[j] + c1 * Bsh[t0 + i][n0 + j];
            }
        }
    }
    size_t s = ((size_t)(b * D_INNER + d) * NCHUNK + c) * D_STATE + n0;
    *(float4*)(Pst + s) = (float4){P[0], P[1], P[2], P[3]};
    *(float4*)(Sst + s) = (float4){S[0], S[1], S[2], S[3]};
}

__global__ __launch_bounds__(256) void scan_combine(
    const float* __restrict__ Pst, const float* __restrict__ Sst,
    float* __restrict__ Hin) {
    int idx = blockIdx.x * 256 + threadIdx.x;
    int bd = idx >> 4;
    int n  = idx & 15;
    float h = 0.f;
#pragma unroll
    for (int c = 0; c < NCHUNK; ++c) {
        size_t s = ((size_t)bd * NCHUNK + c) * D_STATE + n;
        Hin[s] = h;
        h = Pst[s] * h + Sst[s];
    }
}

__global__ __launch_bounds__(256) void scan_apply(
    const float* __restrict__ delta, const u16* __restrict__ uc,
    const float* __restrict__ xd, const u16* __restrict__ xz,
    const float* __restrict__ A_log, const float* __restrict__ Dsk,
    const float* __restrict__ Hin, u16* __restrict__ yg) {
    __shared__ float BCs[CHUNK][32];
    int tid  = threadIdx.x;
    int lane = tid & 63;
    int w    = tid >> 6;
    int dsub = lane & 15;
    int g    = lane >> 4;
    int n0   = g * 4;
    int c = blockIdx.x, b = blockIdx.z;
    int d = blockIdx.y * 64 + w * 16 + dsub;
    int mbase = b * SEQ_L + c * CHUNK;

    {
#pragma unroll
        for (int i = 0; i < 2; i++) {
            int idx = i * 256 + tid;
            int row = idx >> 3, q = idx & 7;
            *(float4*)&BCs[row][q * 4] =
                *(const float4*)(xd + (size_t)(mbase + row) * 96 + DT_RANK + q * 4);
        }
    }
    __syncthreads();

    float a[4];
    {
        float4 a0 = *(const float4*)(A_log + d * D_STATE + n0);
        a[0] = -__expf(a0.x); a[1] = -__expf(a0.y);
        a[2] = -__expf(a0.z); a[3] = -__expf(a0.w);
    }
    float h[4];
    {
        float4 h0 = *(const float4*)(Hin +
            (((size_t)(b * D_INNER + d) * NCHUNK + c) * D_STATE + n0));
        h[0] = h0.x; h[1] = h0.y; h[2] = h0.z; h[3] = h0.w;
    }
    float dsk = Dsk[d];

    for (int t0 = 0; t0 < CHUNK; t0 += 4) {
        float dlv[4], uv[4], zv[4];
#pragma unroll
        for (int i = 0; i < 4; i++) {
            int m = mbase + t0 + i;
            dlv[i] = delta[(size_t)m * D_INNER + d];
            uv[i]  = bf2f(uc[(size_t)m * D_INNER + d]);
            zv[i]  = bf2f(xz[(size_t)m * (2 * D_INNER) + D_INNER + d]);
        }
#pragma unroll
        for (int i = 0; i < 4; i++) {
            int t = t0 + i;
            float c1 = dlv[i] * uv[i];
            float y = 0.f;
#pragma unroll
            for (int j = 0; j < 4; j++) {
                float dA = __expf(dlv[i] * a[j]);
                h[j] = dA * h[j] + c1 * BCs[t][n0 + j];
                y += h[j] * BCs[t][16 + n0 + j];
            }
            y += __shfl_xor(y, 16);
            y += __shfl_xor(y, 32);
            if (g == 0) {
                float z = zv[i];
                float yv = y + uv[i] * dsk;
                float gt = z / (1.f + __expf(-z));
                yg[(size_t)(mbase + t) * D_INNER + d] = f2bf(yv * gt);
            }
        }
    }
}

extern "C" void kernel_launch(void* const* d_in, const int* in_sizes, int n_in,
                              void* d_out, int out_size, void* d_ws, size_t ws_size,
                              hipStream_t stream) {
    const float* x         = (const float*)d_in[0];
    const float* ln_g      = (const float*)d_in[1];
    const float* ln_b      = (const float*)d_in[2];
    const float* in_proj_w = (const float*)d_in[3];
    const float* conv_w    = (const float*)d_in[4];
    const float* conv_b    = (const float*)d_in[5];
    const float* x_proj_w  = (const float*)d_in[6];
    const float* dt_proj_w = (const float*)d_in[7];
    const float* dt_proj_b = (const float*)d_in[8];
    const float* A_log     = (const float*)d_in[9];
    const float* Dsk       = (const float*)d_in[10];
    const float* out_proj_w= (const float*)d_in[11];

    char* ws = (char*)d_ws;
    u16* xn   = (u16*)ws;    ws += (size_t)M_ROWS * D_MODEL * 2;        // 4 MB
    u16* xz   = (u16*)ws;    ws += (size_t)M_ROWS * 2 * D_INNER * 2;    // 16 MB
    u16* ucv  = (u16*)ws;    ws += (size_t)M_ROWS * D_INNER * 2;        // 8 MB
    float* xd = (float*)ws;  ws += (size_t)M_ROWS * 96 * 4;             // 0.75 MB
    u16* dtb  = (u16*)ws;    ws += (size_t)M_ROWS * DT_RANK * 2;        // 0.25 MB
    float* dl = (float*)ws;  ws += (size_t)M_ROWS * D_INNER * 4;        // 16 MB
    u16* yg   = (u16*)ws;    ws += (size_t)M_ROWS * D_INNER * 2;        // 8 MB
    u16* w_in = (u16*)ws;    ws += (size_t)4194304 * 2;                 // 8 MB
    u16* w_out= (u16*)ws;    ws += (size_t)2097152 * 2;                 // 4 MB
    u16* w_xp = (u16*)ws;    ws += (size_t)196608 * 2;                  // 0.375 MB
    u16* w_dt = (u16*)ws;                                               // 0.25 MB

    // Overlays (stream-ordered safe):
    //   Pst -> w_in[0,4MB), Sst -> w_in[4MB,8MB)  (w_in dead after in_proj GEMM)
    //   Hin -> xn (dead after in_proj GEMM)
    //   xdp (x_proj K-split partials, 8 x 0.79MB) -> yg (dead until scan_apply)
    //   opart (out_proj partials, 32MB) -> xz..dl (all dead after scan_apply)
    float* Pst = (float*)w_in;
    float* Sst = (float*)w_in + 1048576;
    float* Hin = (float*)xn;
    float* xdp = (float*)yg;
    float* opart = (float*)xz;

    // 0. weight casts + LayerNorm (one dispatch)
    prep<<<25856 + M_ROWS, 256, 0, stream>>>(
        in_proj_w, out_proj_w, x_proj_w, dt_proj_w, w_in, w_out, w_xp, w_dt,
        x, ln_g, ln_b, xn);
    // 1. xz = xn @ in_proj_w^T  (M=2048, N=4096, K=1024) — 64x128 tile, 1024 blocks
    gemm_lds<64, 128, 4, 2, 0><<<dim3(4096 / 128, M_ROWS / 64, 1), 256, 0, stream>>>(
        (const __bf16*)xn, (const __bf16*)w_in, D_MODEL, D_MODEL / 32, 2 * D_INNER,
        nullptr, xz);
    // 2. causal depthwise conv + SiLU on u half
    conv_silu<<<(M_ROWS * D_INNER) / 256, 256, 0, stream>>>(xz, conv_w, conv_b, ucv);
    // 3. x_dbl partials = u @ x_proj_w^T  (N=96, K-split by 8) + fused reduce/cast
    gemm_bt<1><<<dim3(2, 32, 8), 256, 0, stream>>>(
        (const __bf16*)ucv, (const __bf16*)w_xp, D_INNER, D_INNER / 8, 96, 96,
        xdp, nullptr);
    xdbl_reduce<<<(M_ROWS * 96) / 256, 256, 0, stream>>>(xdp, xd, dtb);
    // 4. delta = softplus(dt @ dt_proj_w^T + dt_proj_b)  (K=64, N=2048)
    gemm_bt<2><<<dim3(32, 32, 1), 256, 0, stream>>>(
        (const __bf16*)dtb, (const __bf16*)w_dt, DT_RANK, DT_RANK, D_INNER,
        D_INNER, dl, dt_proj_b);
    // 5. chunked selective scan (4 states/thread, 1024 blocks, unroll-4)
    dim3 sgrid(NCHUNK, D_INNER / 64, NBATCH);
    scan_chunk<<<sgrid, 256, 0, stream>>>(dl, ucv, xd, A_log, Pst, Sst);
    scan_combine<<<(NBATCH * D_INNER * D_STATE) / 256, 256, 0, stream>>>(Pst, Sst, Hin);
    scan_apply<<<sgrid, 256, 0, stream>>>(dl, ucv, xd, xz, A_log, Dsk, Hin, yg);
    // 6. out_proj partials (K=2048 split x4) + reduce w/ residual
    gemm_lds<64, 128, 4, 2, 4><<<dim3(1024 / 128, M_ROWS / 64, 4), 256, 0, stream>>>(
        (const __bf16*)yg, (const __bf16*)w_out, D_INNER, D_INNER / 4 / 32, D_MODEL,
        opart, nullptr);
    out_reduce<<<(M_ROWS * D_MODEL / 4) / 256, 256, 0, stream>>>(
        opart, x, (float*)d_out);
}

// Round 11
// 268.589 us; speedup vs baseline: 1.0596x; 1.0145x over previous
//
#include <hip/hip_runtime.h>

#define D_MODEL 1024
#define D_STATE 16
#define D_INNER 2048
#define DT_RANK 64
#define NBATCH 2
#define SEQ_L 1024
#define M_ROWS (NBATCH * SEQ_L)   // 2048
#define CHUNK 32
#define NCHUNK (SEQ_L / CHUNK)    // 32

typedef __bf16 bf16x8 __attribute__((ext_vector_type(8)));
typedef float f32x4 __attribute__((ext_vector_type(4)));
typedef unsigned short u16;
typedef unsigned int u32;

__device__ __forceinline__ float bf2f(u16 h) {
    return __uint_as_float(((unsigned)h) << 16);
}
__device__ __forceinline__ u16 f2bf(float f) {
    unsigned u = __float_as_uint(f);
    u += 0x7fff + ((u >> 16) & 1);   // round-to-nearest-even
    return (u16)(u >> 16);
}

// ---------------- prep: weight casts (blocks 0..25855) + LayerNorm (rest) ----------------
__global__ __launch_bounds__(256) void prep(
    const float* __restrict__ s0, const float* __restrict__ s1,
    const float* __restrict__ s2, const float* __restrict__ s3,
    u16* __restrict__ d0, u16* __restrict__ d1,
    u16* __restrict__ d2, u16* __restrict__ d3,
    const float* __restrict__ x, const float* __restrict__ g,
    const float* __restrict__ b, u16* __restrict__ xn) {
    int blk = blockIdx.x;
    if (blk < 25856) {
        int idx = blk * 256 + threadIdx.x;
        if (idx < 4194304) {
            d0[idx] = f2bf(s0[idx]);
        } else if (idx < 6291456) {
            int i = idx - 4194304; d1[i] = f2bf(s1[i]);
        } else if (idx < 6488064) {
            int i = idx - 6291456; d2[i] = f2bf(s2[i]);
        } else {
            int i = idx - 6488064; d3[i] = f2bf(s3[i]);
        }
        return;
    }
    int row = blk - 25856;
    const float4* xr = (const float4*)(x + (size_t)row * D_MODEL);
    float4 v = xr[threadIdx.x];
    float s  = v.x + v.y + v.z + v.w;
    float ss = v.x * v.x + v.y * v.y + v.z * v.z + v.w * v.w;
#pragma unroll
    for (int off = 32; off > 0; off >>= 1) {
        s  += __shfl_down(s,  off, 64);
        ss += __shfl_down(ss, off, 64);
    }
    __shared__ float sh_s[4], sh_ss[4];
    int wid = threadIdx.x >> 6;
    if ((threadIdx.x & 63) == 0) { sh_s[wid] = s; sh_ss[wid] = ss; }
    __syncthreads();
    float mu  = (sh_s[0] + sh_s[1] + sh_s[2] + sh_s[3]) * (1.0f / D_MODEL);
    float var = (sh_ss[0] + sh_ss[1] + sh_ss[2] + sh_ss[3]) * (1.0f / D_MODEL) - mu * mu;
    float rs = rsqrtf(var + 1e-5f);
    int c0 = threadIdx.x * 4;
    float vv[4] = {v.x, v.y, v.z, v.w};
#pragma unroll
    for (int j = 0; j < 4; j++) {
        int c = c0 + j;
        float o = (vv[j] - mu) * rs * g[c] + b[c];
        xn[(size_t)row * D_MODEL + c] = f2bf(o);
    }
}

// ============ LDS-staged B^T GEMM (m97 structure) ============
// K-split over blockIdx.z (Ksteps iters from z*Ksteps*32).
// MODE 0: bf16 store. MODE 4: f32 partial store to outF + z*M_ROWS*ldC.
template <int BM, int BN, int WM, int WN, int MODE>
__global__ __launch_bounds__(256) void gemm_lds(
    const __bf16* __restrict__ A, const __bf16* __restrict__ W,
    int K, int Ksteps, int ldC,
    float* __restrict__ outF, u16* __restrict__ outB) {
    constexpr int WCOLS = BN / (WN * 16);
    __shared__ __bf16 As[BM * 32];
    __shared__ __bf16 Bs[BN * 32];
    int tid  = threadIdx.x;
    int lane = tid & 63;
    int wid  = tid >> 6;
    int l16  = lane & 15;
    int quad = lane >> 4;
    int wr = wid / WCOLS;
    int wc = wid % WCOLS;
    int m0 = blockIdx.y * BM;
    int n0 = blockIdx.x * BN;
    int kbase = blockIdx.z * Ksteps * 32;

    f32x4 acc[WM][WN];
#pragma unroll
    for (int mi = 0; mi < WM; mi++)
#pragma unroll
        for (int nj = 0; nj < WN; nj++)
            acc[mi][nj] = (f32x4){0.f, 0.f, 0.f, 0.f};

    for (int ki = 0; ki < Ksteps; ki++) {
        int k0 = kbase + ki * 32;
        __syncthreads();
#pragma unroll
        for (int i = 0; i < BM / 64; i++) {
            int t   = i * 256 + tid;
            int row = t >> 2;
            int cg  = (t & 3) ^ ((row >> 1) & 3);
            __builtin_amdgcn_global_load_lds(
                (const __attribute__((address_space(1))) u32*)(A + (size_t)(m0 + row) * K + k0 + cg * 8),
                (__attribute__((address_space(3))) u32*)(As + (i * 256 + wid * 64) * 8),
                16, 0, 0);
        }
#pragma unroll
        for (int i = 0; i < BN / 64; i++) {
            int t   = i * 256 + tid;
            int row = t >> 2;
            int cg  = (t & 3) ^ ((row >> 1) & 3);
            __builtin_amdgcn_global_load_lds(
                (const __attribute__((address_space(1))) u32*)(W + (size_t)(n0 + row) * K + k0 + cg * 8),
                (__attribute__((address_space(3))) u32*)(Bs + (i * 256 + wid * 64) * 8),
                16, 0, 0);
        }
        __syncthreads();

        bf16x8 af[WM], bfr[WN];
#pragma unroll
        for (int mi = 0; mi < WM; mi++) {
            int r  = wr * WM * 16 + mi * 16 + l16;
            int cg = quad ^ ((r >> 1) & 3);
            af[mi] = *(const bf16x8*)(As + r * 32 + cg * 8);
        }
#pragma unroll
        for (int nj = 0; nj < WN; nj++) {
            int r  = wc * WN * 16 + nj * 16 + l16;
            int cg = quad ^ ((r >> 1) & 3);
            bfr[nj] = *(const bf16x8*)(Bs + r * 32 + cg * 8);
        }
#pragma unroll
        for (int mi = 0; mi < WM; mi++)
#pragma unroll
            for (int nj = 0; nj < WN; nj++)
                acc[mi][nj] = __builtin_amdgcn_mfma_f32_16x16x32_bf16(
                    af[mi], bfr[nj], acc[mi][nj], 0, 0, 0);
    }

    float* outP = (MODE == 4) ? outF + (size_t)blockIdx.z * M_ROWS * ldC : outF;
#pragma unroll
    for (int mi = 0; mi < WM; mi++) {
#pragma unroll
        for (int nj = 0; nj < WN; nj++) {
            int col = n0 + wc * WN * 16 + nj * 16 + l16;
#pragma unroll
            for (int r = 0; r < 4; r++) {
                int row = m0 + wr * WM * 16 + mi * 16 + quad * 4 + r;
                float v = acc[mi][nj][r];
                if (MODE == 0) {
                    outB[(size_t)row * ldC + col] = f2bf(v);
                } else {
                    outP[(size_t)row * ldC + col] = v;
                }
            }
        }
    }
}

// ---------------- out_proj partial reduce + residual ----------------
__global__ __launch_bounds__(256) void out_reduce(
    const float* __restrict__ p, const float* __restrict__ x,
    float* __restrict__ out) {
    int idx = blockIdx.x * 256 + threadIdx.x;   // float4 index
    const int N = M_ROWS * D_MODEL;
    float4 a = ((const float4*)p)[idx];
    float4 b = ((const float4*)(p + N))[idx];
    float4 c = ((const float4*)(p + 2 * N))[idx];
    float4 d = ((const float4*)(p + 3 * N))[idx];
    float4 r = ((const float4*)x)[idx];
    float4 o;
    o.x = a.x + b.x + c.x + d.x + r.x;
    o.y = a.y + b.y + c.y + d.y + r.y;
    o.z = a.z + b.z + c.z + d.z + r.z;
    o.w = a.w + b.w + c.w + d.w + r.w;
    ((float4*)out)[idx] = o;
}

// ---------------- small direct GEMM ----------------
// MODE 1: partial f32 to outF + z*M_ROWS*96, col<Nw.
// MODE 2: softplus(acc+auxF[n]) -> bf16 outB16.
template <int MODE>
__global__ __launch_bounds__(256) void gemm_bt(
    const __bf16* __restrict__ A, const __bf16* __restrict__ W,
    int K, int Ksplit, int Nw, int ldC,
    float* __restrict__ outF, u16* __restrict__ outB16,
    const float* __restrict__ auxF) {
    int lane = threadIdx.x & 63;
    int wid  = threadIdx.x >> 6;
    int m0 = blockIdx.y * 64;
    int n0 = blockIdx.x * 64;
    int kc = blockIdx.z;
    int l16  = lane & 15;
    int quad = lane >> 4;
    int mrow = m0 + wid * 16 + l16;

    const __bf16* ap = A + (size_t)mrow * K + kc * Ksplit + quad * 8;
    const __bf16* wp[4];
#pragma unroll
    for (int j = 0; j < 4; j++) {
        int nc = n0 + j * 16 + l16;
        if (nc > Nw - 1) nc = Nw - 1;
        wp[j] = W + (size_t)nc * K + kc * Ksplit + quad * 8;
    }
    f32x4 acc[4];
#pragma unroll
    for (int j = 0; j < 4; j++) acc[j] = (f32x4){0.f, 0.f, 0.f, 0.f};

    for (int k = 0; k < Ksplit; k += 32) {
        bf16x8 a = *(const bf16x8*)ap;
        ap += 32;
#pragma unroll
        for (int j = 0; j < 4; j++) {
            bf16x8 bfr = *(const bf16x8*)wp[j];
            wp[j] += 32;
            acc[j] = __builtin_amdgcn_mfma_f32_16x16x32_bf16(a, bfr, acc[j], 0, 0, 0);
        }
    }
    float* out = (MODE == 1) ? outF + (size_t)kc * (M_ROWS * 96) : outF;
#pragma unroll
    for (int j = 0; j < 4; j++) {
        int col = n0 + j * 16 + l16;
#pragma unroll
        for (int r = 0; r < 4; r++) {
            int row = m0 + wid * 16 + quad * 4 + r;
            float v = acc[j][r];
            if (MODE == 1) {
                if (col < Nw) out[(size_t)row * ldC + col] = v;
            } else {
                float t = v + auxF[col];
                float sp = (t > 20.f) ? t : log1pf(__expf(t));
                outB16[(size_t)row * ldC + col] = f2bf(sp);
            }
        }
    }
}

// ---------------- reduce 8 K-split partials -> xd, fused dt bf16 cast ----------------
__global__ __launch_bounds__(256) void xdbl_reduce(
    const float* __restrict__ xdp, float* __restrict__ xd,
    u16* __restrict__ dtb) {
    int idx = blockIdx.x * 256 + threadIdx.x;   // < M_ROWS*96
    const int N = M_ROWS * 96;
    float v = 0.f;
#pragma unroll
    for (int i = 0; i < 8; i++) v += xdp[idx + i * N];
    xd[idx] = v;
    int mrow = idx / 96;
    int r = idx - mrow * 96;
    if (r < DT_RANK) dtb[mrow * DT_RANK + r] = f2bf(v);
}

// ---------------- causal depthwise conv (width 4) + bias + SiLU ----------------
__global__ __launch_bounds__(256) void conv_silu(
    const u16* __restrict__ xz, const float* __restrict__ cw,
    const float* __restrict__ cb, u16* __restrict__ uc) {
    int idx = blockIdx.x * 256 + threadIdx.x;
    int d = idx & (D_INNER - 1);
    int m = idx >> 11;
    int t = m & (SEQ_L - 1);
    float s = cb[d];
#pragma unroll
    for (int j = 0; j < 4; j++) {
        int tt = t - 3 + j;
        if (tt >= 0) {
            s += cw[d * 4 + j] *
                 bf2f(xz[(size_t)(m - 3 + j) * (2 * D_INNER) + d]);
        }
    }
    float sig = 1.f / (1.f + __expf(-s));
    uc[idx] = f2bf(s * sig);
}

// ================= chunked selective scan — 4 states/thread, CHUNK=32 =================
// delta (dl) is bf16. grid = (NCHUNK=32, D_INNER/64, NBATCH) = 2048 blocks (8/CU).
__global__ __launch_bounds__(256) void scan_chunk(
    const u16* __restrict__ delta, const u16* __restrict__ uc,
    const float* __restrict__ xd, const float* __restrict__ A_log,
    float* __restrict__ Pst, float* __restrict__ Sst) {
    __shared__ float Bsh[CHUNK][16];
    int tid  = threadIdx.x;
    int lane = tid & 63;
    int w    = tid >> 6;
    int dsub = lane & 15;
    int g    = lane >> 4;
    int n0   = g * 4;
    int c = blockIdx.x, b = blockIdx.z;
    int d = blockIdx.y * 64 + w * 16 + dsub;
    int mbase = b * SEQ_L + c * CHUNK;

    if (tid < CHUNK * 4) {   // stage B rows: 32 x 16 floats
        int row = tid >> 2, q = tid & 3;
        *(float4*)&Bsh[row][q * 4] =
            *(const float4*)(xd + (size_t)(mbase + row) * 96 + DT_RANK + q * 4);
    }
    __syncthreads();

    float a[4];
    {
        float4 a0 = *(const float4*)(A_log + d * D_STATE + n0);
        a[0] = -__expf(a0.x); a[1] = -__expf(a0.y);
        a[2] = -__expf(a0.z); a[3] = -__expf(a0.w);
    }
    float P[4] = {1.f, 1.f, 1.f, 1.f}, S[4] = {0.f, 0.f, 0.f, 0.f};

    for (int t0 = 0; t0 < CHUNK; t0 += 4) {
        float dlv[4], uv[4];
#pragma unroll
        for (int i = 0; i < 4; i++) {
            int m = mbase + t0 + i;
            dlv[i] = bf2f(delta[(size_t)m * D_INNER + d]);
            uv[i]  = bf2f(uc[(size_t)m * D_INNER + d]);
        }
#pragma unroll
        for (int i = 0; i < 4; i++) {
            float c1 = dlv[i] * uv[i];
#pragma unroll
            for (int j = 0; j < 4; j++) {
                float dA = __expf(dlv[i] * a[j]);
                P[j] *= dA;
                S[j] = dA * S[j] + c1 * Bsh[t0 + i][n0 + j];
            }
        }
    }
    size_t s = ((size_t)(b * D_INNER + d) * NCHUNK + c) * D_STATE + n0;
    *(float4*)(Pst + s) = (float4){P[0], P[1], P[2], P[3]};
    *(float4*)(Sst + s) = (float4){S[0], S[1], S[2], S[3]};
}

__global__ __launch_bounds__(256) void scan_combine(
    const float* __restrict__ Pst, const float* __restrict__ Sst,
    float* __restrict__ Hin) {
    int idx = blockIdx.x * 256 + threadIdx.x;   // < NBATCH*D_INNER*D_STATE
    int bd = idx >> 4;
    int n  = idx & 15;
    float h = 0.f;
#pragma unroll
    for (int c = 0; c < NCHUNK; ++c) {
        size_t s = ((size_t)bd * NCHUNK + c) * D_STATE + n;
        Hin[s] = h;
        h = Pst[s] * h + Sst[s];
    }
}

__global__ __launch_bounds__(256) void scan_apply(
    const u16* __restrict__ delta, const u16* __restrict__ uc,
    const float* __restrict__ xd, const u16* __restrict__ xz,
    const float* __restrict__ A_log, const float* __restrict__ Dsk,
    const float* __restrict__ Hin, u16* __restrict__ yg) {
    __shared__ float BCs[CHUNK][32];
    int tid  = threadIdx.x;
    int lane = tid & 63;
    int w    = tid >> 6;
    int dsub = lane & 15;
    int g    = lane >> 4;
    int n0   = g * 4;
    int c = blockIdx.x, b = blockIdx.z;
    int d = blockIdx.y * 64 + w * 16 + dsub;
    int mbase = b * SEQ_L + c * CHUNK;

    {   // stage B+C rows: 32 x 32 floats = 256 float4s
        int row = tid >> 3, q = tid & 7;
        *(float4*)&BCs[row][q * 4] =
            *(const float4*)(xd + (size_t)(mbase + row) * 96 + DT_RANK + q * 4);
    }
    __syncthreads();

    float a[4];
    {
        float4 a0 = *(const float4*)(A_log + d * D_STATE + n0);
        a[0] = -__expf(a0.x); a[1] = -__expf(a0.y);
        a[2] = -__expf(a0.z); a[3] = -__expf(a0.w);
    }
    float h[4];
    {
        float4 h0 = *(const float4*)(Hin +
            (((size_t)(b * D_INNER + d) * NCHUNK + c) * D_STATE + n0));
        h[0] = h0.x; h[1] = h0.y; h[2] = h0.z; h[3] = h0.w;
    }
    float dsk = Dsk[d];

    for (int t0 = 0; t0 < CHUNK; t0 += 4) {
        float dlv[4], uv[4], zv[4];
#pragma unroll
        for (int i = 0; i < 4; i++) {
            int m = mbase + t0 + i;
            dlv[i] = bf2f(delta[(size_t)m * D_INNER + d]);
            uv[i]  = bf2f(uc[(size_t)m * D_INNER + d]);
            zv[i]  = bf2f(xz[(size_t)m * (2 * D_INNER) + D_INNER + d]);
        }
#pragma unroll
        for (int i = 0; i < 4; i++) {
            int t = t0 + i;
            float c1 = dlv[i] * uv[i];
            float y = 0.f;
#pragma unroll
            for (int j = 0; j < 4; j++) {
                float dA = __expf(dlv[i] * a[j]);
                h[j] = dA * h[j] + c1 * BCs[t][n0 + j];
                y += h[j] * BCs[t][16 + n0 + j];
            }
            y += __shfl_xor(y, 16);
            y += __shfl_xor(y, 32);
            if (g == 0) {
                float z = zv[i];
                float yv = y + uv[i] * dsk;
                float gt = z / (1.f + __expf(-z));
                yg[(size_t)(mbase + t) * D_INNER + d] = f2bf(yv * gt);
            }
        }
    }
}

extern "C" void kernel_launch(void* const* d_in, const int* in_sizes, int n_in,
                              void* d_out, int out_size, void* d_ws, size_t ws_size,
                              hipStream_t stream) {
    const float* x         = (const float*)d_in[0];
    const float* ln_g      = (const float*)d_in[1];
    const float* ln_b      = (const float*)d_in[2];
    const float* in_proj_w = (const float*)d_in[3];
    const float* conv_w    = (const float*)d_in[4];
    const float* conv_b    = (const float*)d_in[5];
    const float* x_proj_w  = (const float*)d_in[6];
    const float* dt_proj_w = (const float*)d_in[7];
    const float* dt_proj_b = (const float*)d_in[8];
    const float* A_log     = (const float*)d_in[9];
    const float* Dsk       = (const float*)d_in[10];
    const float* out_proj_w= (const float*)d_in[11];

    // ws is 256 MiB (verified: harness poison fill WRITE_SIZE). ~130 MB used,
    // every buffer gets its own region — no overlays.
    char* ws = (char*)d_ws;
    u16* xn   = (u16*)ws;    ws += (size_t)M_ROWS * D_MODEL * 2;        // 4 MB
    u16* xz   = (u16*)ws;    ws += (size_t)M_ROWS * 2 * D_INNER * 2;    // 16 MB
    u16* ucv  = (u16*)ws;    ws += (size_t)M_ROWS * D_INNER * 2;        // 8 MB
    float* xd = (float*)ws;  ws += (size_t)M_ROWS * 96 * 4;             // 0.75 MB
    u16* dtb  = (u16*)ws;    ws += (size_t)M_ROWS * DT_RANK * 2;        // 0.25 MB
    u16* dl   = (u16*)ws;    ws += (size_t)M_ROWS * D_INNER * 2;        // 8 MB (bf16)
    u16* yg   = (u16*)ws;    ws += (size_t)M_ROWS * D_INNER * 2;        // 8 MB
    u16* w_in = (u16*)ws;    ws += (size_t)4194304 * 2;                 // 8 MB
    u16* w_out= (u16*)ws;    ws += (size_t)2097152 * 2;                 // 4 MB
    u16* w_xp = (u16*)ws;    ws += (size_t)196608 * 2;                  // 0.375 MB
    u16* w_dt = (u16*)ws;    ws += (size_t)131072 * 2;                  // 0.25 MB
    float* Pst = (float*)ws; ws += (size_t)NBATCH * D_INNER * D_STATE * NCHUNK * 4; // 8 MB
    float* Sst = (float*)ws; ws += (size_t)NBATCH * D_INNER * D_STATE * NCHUNK * 4; // 8 MB
    float* Hin = (float*)ws; ws += (size_t)NBATCH * D_INNER * D_STATE * NCHUNK * 4; // 8 MB
    float* xdp = (float*)ws; ws += (size_t)8 * M_ROWS * 96 * 4;         // 6 MB
    float* opart = (float*)ws;                                          // 32 MB

    // 0. weight casts + LayerNorm (one dispatch)
    prep<<<25856 + M_ROWS, 256, 0, stream>>>(
        in_proj_w, out_proj_w, x_proj_w, dt_proj_w, w_in, w_out, w_xp, w_dt,
        x, ln_g, ln_b, xn);
    // 1. xz = xn @ in_proj_w^T  (M=2048, N=4096, K=1024) — 64x128 tile, 1024 blocks
    gemm_lds<64, 128, 4, 2, 0><<<dim3(4096 / 128, M_ROWS / 64, 1), 256, 0, stream>>>(
        (const __bf16*)xn, (const __bf16*)w_in, D_MODEL, D_MODEL / 32, 2 * D_INNER,
        nullptr, xz);
    // 2. causal depthwise conv + SiLU on u half
    conv_silu<<<(M_ROWS * D_INNER) / 256, 256, 0, stream>>>(xz, conv_w, conv_b, ucv);
    // 3. x_dbl partials = u @ x_proj_w^T  (N=96, K-split by 8) + fused reduce/cast
    gemm_bt<1><<<dim3(2, 32, 8), 256, 0, stream>>>(
        (const __bf16*)ucv, (const __bf16*)w_xp, D_INNER, D_INNER / 8, 96, 96,
        xdp, nullptr, nullptr);
    xdbl_reduce<<<(M_ROWS * 96) / 256, 256, 0, stream>>>(xdp, xd, dtb);
    // 4. delta = softplus(dt @ dt_proj_w^T + dt_proj_b) -> bf16
    gemm_bt<2><<<dim3(32, 32, 1), 256, 0, stream>>>(
        (const __bf16*)dtb, (const __bf16*)w_dt, DT_RANK, DT_RANK, D_INNER,
        D_INNER, nullptr, dl, dt_proj_b);
    // 5. chunked selective scan (CHUNK=32, 2048 blocks, 8/CU)
    dim3 sgrid(NCHUNK, D_INNER / 64, NBATCH);
    scan_chunk<<<sgrid, 256, 0, stream>>>(dl, ucv, xd, A_log, Pst, Sst);
    scan_combine<<<(NBATCH * D_INNER * D_STATE) / 256, 256, 0, stream>>>(Pst, Sst, Hin);
    scan_apply<<<sgrid, 256, 0, stream>>>(dl, ucv, xd, xz, A_log, Dsk, Hin, yg);
    // 6. out_proj partials (K=2048 split x4) + reduce w/ residual
    gemm_lds<64, 128, 4, 2, 4><<<dim3(1024 / 128, M_ROWS / 64, 4), 256, 0, stream>>>(
        (const __bf16*)yg, (const __bf16*)w_out, D_INNER, D_INNER / 4 / 32, D_MODEL,
        opart, nullptr);
    out_reduce<<<(M_ROWS * D_MODEL / 4) / 256, 256, 0, stream>>>(
        opart, x, (float*)d_out);
}